// Round 1
// baseline (59.252 us; speedup 1.0000x reference)
//
#include <hip/hip_runtime.h>

// QuantumLayer analytic solution.
//
// Reference circuit: RY(x_i)|0> product state, then L layers of
// [RZ(q_weights) on all wires; CNOT chain 0->1->...->n-1], then <PauliZ_w>.
//
// RZ layers are diagonal phases (unit modulus) and the CNOT chain is a basis
// permutation P (prefix-xor over wire bits, wire 0 = MSB). Neither changes
// |amplitude|^2 except by permuting indices, so q_weights drops out entirely:
//   probs_final[p] = probs_0[P^{-L}(p)]
// probs_0 is a product distribution with E[z_i] = cos^2(x/2)-sin^2(x/2) = cos(x_i).
// Bit w of P^L(bits) is the XOR of a fixed set S_w of input bits (over GF(2),
// P^L's row w; for L=2 this is {w, w-2, w-4, ...}). z of an XOR = product of z,
// and bits are independent, so:
//   out[b,w] = prod_{m in S_w} cos(x[b,m])
// Masks S_w are computed generically for runtime L (trivial XOR recurrence).

constexpr int N = 10;  // n wires (x is [B, 10] per reference setup)

__global__ __launch_bounds__(64) void qlayer_kernel(const float* __restrict__ x,
                                                    float* __restrict__ out,
                                                    int B, int L) {
    constexpr int ROWS = 64;
    __shared__ float sx[ROWS][N + 1];  // +1 pad: break LDS bank aliasing on stride-N access
    const int row0 = blockIdx.x * ROWS;

    // Coalesced global load -> padded LDS
    for (int i = threadIdx.x; i < ROWS * N; i += blockDim.x) {
        const int g = row0 * N + i;
        const float v = (g < B * N) ? x[g] : 0.0f;
        sx[i / N][i % N] = v;
    }
    __syncthreads();

    // masks[w] = set of input wires whose bits XOR into output wire w after
    // L applications of the prefix-xor permutation.
    unsigned mask[N];
#pragma unroll
    for (int w = 0; w < N; ++w) mask[w] = 1u << w;
    for (int l = 0; l < L; ++l) {
        unsigned acc = 0;
#pragma unroll
        for (int w = 0; w < N; ++w) { acc ^= mask[w]; mask[w] = acc; }
    }

    const int row = row0 + (int)threadIdx.x;
    float res[N];
    if (row < B) {
        float c[N];
#pragma unroll
        for (int i = 0; i < N; ++i) c[i] = cosf(sx[threadIdx.x][i]);
#pragma unroll
        for (int w = 0; w < N; ++w) {
            float p = 1.0f;
#pragma unroll
            for (int m = 0; m < N; ++m)
                if (mask[w] & (1u << m)) p *= c[m];
            res[w] = p;
        }
    }
    __syncthreads();

    // Stage results in LDS, then coalesced store
    if (row < B) {
#pragma unroll
        for (int w = 0; w < N; ++w) sx[threadIdx.x][w] = res[w];
    }
    __syncthreads();
    for (int i = threadIdx.x; i < ROWS * N; i += blockDim.x) {
        const int g = row0 * N + i;
        if (g < B * N) out[g] = sx[i / N][i % N];
    }
}

extern "C" void kernel_launch(void* const* d_in, const int* in_sizes, int n_in,
                              void* d_out, int out_size, void* d_ws, size_t ws_size,
                              hipStream_t stream) {
    const float* x = (const float*)d_in[0];
    // d_in[1] = q_weights: provably unused — RZ phases cancel in |amplitude|^2.
    const int B = in_sizes[0] / N;
    const int L = in_sizes[1] / N;  // number of layers (2 in reference setup)
    const int blocks = (B + 63) / 64;
    qlayer_kernel<<<blocks, 64, 0, stream>>>(x, (float*)d_out, B, L);
}

// Round 2
// 54.941 us; speedup vs baseline: 1.0785x; 1.0785x over previous
//
#include <hip/hip_runtime.h>

// QuantumLayer analytic solution (see round-0 derivation).
//
// RZ layers are unit-modulus diagonal phases and the CNOT chain is a basis
// permutation, so q_weights cancels in |amplitude|^2. The product state gives
// independent wire-bits with E[z_i] = cos(x_i); after L prefix-xor
// permutations, output wire w is the XOR of wire-set S_w, so
//   out[b,w] = prod_{m in S_w} cos(x[b,m])
// Masks S_w computed generically for runtime L (XOR prefix recurrence).
//
// This round: no LDS / no barriers (rows are 40 B = 5 x float2, 8-aligned;
// a wave's 5 dwordx2 loads cover one contiguous 2560 B span -> L1 coalesces),
// native __cosf (v_cos_f32 path; |x|~N(0,1), abs err ~1e-6 vs 2e-2 threshold).

constexpr int N = 10;  // n wires (x is [B, 10] per reference setup)

__global__ __launch_bounds__(64) void qlayer_kernel(const float* __restrict__ x,
                                                    float* __restrict__ out,
                                                    int B, int L) {
    const int row = blockIdx.x * 64 + threadIdx.x;
    if (row >= B) return;

    // Load this row as 5 x float2 (40 B, 8-byte aligned for every row).
    const float2* xr = (const float2*)(x + (size_t)row * N);
    float c[N];
#pragma unroll
    for (int i = 0; i < N / 2; ++i) {
        float2 v = xr[i];
        c[2 * i]     = __cosf(v.x);
        c[2 * i + 1] = __cosf(v.y);
    }

    // masks[w] = input wires whose bits XOR into output wire w after L layers.
    unsigned mask[N];
#pragma unroll
    for (int w = 0; w < N; ++w) mask[w] = 1u << w;
    for (int l = 0; l < L; ++l) {
        unsigned acc = 0;
#pragma unroll
        for (int w = 0; w < N; ++w) { acc ^= mask[w]; mask[w] = acc; }
    }

    float2* orow = (float2*)(out + (size_t)row * N);
#pragma unroll
    for (int i = 0; i < N / 2; ++i) {
        float2 r;
        float p0 = 1.0f, p1 = 1.0f;
#pragma unroll
        for (int m = 0; m < N; ++m) {
            if (mask[2 * i] & (1u << m)) p0 *= c[m];
            if (mask[2 * i + 1] & (1u << m)) p1 *= c[m];
        }
        r.x = p0; r.y = p1;
        orow[i] = r;
    }
}

extern "C" void kernel_launch(void* const* d_in, const int* in_sizes, int n_in,
                              void* d_out, int out_size, void* d_ws, size_t ws_size,
                              hipStream_t stream) {
    const float* x = (const float*)d_in[0];
    // d_in[1] = q_weights: provably unused — RZ phases cancel in |amplitude|^2.
    const int B = in_sizes[0] / N;
    const int L = in_sizes[1] / N;  // number of layers (2 in reference setup)
    const int blocks = (B + 63) / 64;
    qlayer_kernel<<<blocks, 64, 0, stream>>>(x, (float*)d_out, B, L);
}